// Round 4
// baseline (523.791 us; speedup 1.0000x reference)
//
#include <hip/hip_runtime.h>
#include <hip/hip_bf16.h>

typedef unsigned short u16;
typedef unsigned int u32;
typedef unsigned long long u64;
typedef float f32x4 __attribute__((ext_vector_type(4)));
typedef u16 u16x8 __attribute__((ext_vector_type(8)));
typedef _Float16 h16x8 __attribute__((ext_vector_type(8)));

#define L_ 343
#define LL_ 117649
#define H_ 8
#define HD_ 32
#define NW_ 128
#define LP_ 352          // padded key count (22*16)
#define NF_ 22           // col fragments in S
#define NKST 40          // row stride (u16): 80B, 16B-aligned
#define VTST 360         // vT row stride (u16): 720B, 16B-aligned
#define PMW 12           // u32 words per packed-mask row

__device__ __forceinline__ u16 f2h(float f) {
    _Float16 h = (_Float16)f;
    return __builtin_bit_cast(u16, h);
}

// ---------------- K0: convert + transpose weights to f16 [n][k] ----------------
__global__ __launch_bounds__(256) void cvtw_kernel(
    const float* __restrict__ Wq, const float* __restrict__ Wk,
    const float* __restrict__ Wv, const float* __restrict__ Ww,
    u16* __restrict__ wt)
{
    const float* Ws[4] = {Wq, Wk, Wv, Ww};
    const int mat = blockIdx.y;
    const float* W = Ws[mat];
    int idx = blockIdx.x * 256 + threadIdx.x;   // [0, 16384)
    int n  = idx >> 6;
    int kb = (idx & 63) * 4;
    u16* d = wt + mat * 65536 + n * 256 + kb;
    #pragma unroll
    for (int j = 0; j < 4; ++j)
        d[j] = f2h(W[(kb + j) * 256 + n]);
}

// ---------------- K1: CPB MLP lookup table (2197 x 8, fp32) ----------------
__global__ __launch_bounds__(256) void cpb_table_kernel(
    const float* __restrict__ W1, const float* __restrict__ b1,
    const float* __restrict__ W2, const float* __restrict__ b2,
    float* __restrict__ table)
{
    __shared__ float red[256 * 9];
    const int e = blockIdx.x;
    const int t = threadIdx.x;
    int t0 = e / 169, rem = e % 169, t1 = rem / 13, t2 = rem % 13;
    int tt[3] = {t0, t1, t2};
    float li[3];
    #pragma unroll
    for (int i = 0; i < 3; ++i) {
        float c = (float)(tt[i] - 6);
        li[i] = copysignf(log2f(1.0f + fabsf(c)) * (1.0f / 3.0f), c);
    }
    float p[8] = {0,0,0,0,0,0,0,0};
    for (int jj = t; jj < 512; jj += 256) {
        float hs = li[0]*W1[jj] + li[1]*W1[512+jj] + li[2]*W1[1024+jj] + b1[jj];
        float hid = fmaxf(hs, 0.0f);
        #pragma unroll
        for (int o = 0; o < 8; ++o) p[o] += hid * W2[jj*8 + o];
    }
    #pragma unroll
    for (int o = 0; o < 8; ++o) red[t*9 + o] = p[o];
    __syncthreads();
    for (int s = 128; s > 0; s >>= 1) {
        if (t < s) {
            #pragma unroll
            for (int o = 0; o < 8; ++o) red[t*9+o] += red[(t+s)*9+o];
        }
        __syncthreads();
    }
    if (t < 8)
        table[e*8 + t] = 16.0f / (1.0f + __expf(-(red[t] + b2[t])));
}

// ---------------- K2: (i,j) -> table-entry index, u16 ----------------
__global__ __launch_bounds__(256) void e16_kernel(
    const float* __restrict__ idxf, u16* __restrict__ e16)
{
    int g = blockIdx.x * 256 + threadIdx.x;
    if (g >= LL_) return;
    int a = (int)idxf[g*3 + 0] + 6;
    int b = (int)idxf[g*3 + 1] + 6;
    int c = (int)idxf[g*3 + 2] + 6;
    e16[g] = (u16)((a * 13 + b) * 13 + c);
}

// ---------------- K3: pack mask to bits (dtype auto-detect) ----------------
__global__ __launch_bounds__(256) void pack_mask_kernel(
    const u32* __restrict__ m32, u64* __restrict__ pm)
{
    // detect: int32 bool words are 0/1 -> upper 3 bytes always 0.
    // uint8 bool: P(first 64 words all have zero upper bytes) = 0.9^192 ~ 2e-9.
    bool isU8 = false;
    for (int i = 0; i < 64; ++i)
        if (m32[i] & 0xFFFFFF00u) isU8 = true;
    const unsigned char* m8 = (const unsigned char*)m32;
    int row = blockIdx.x * 4 + (threadIdx.x >> 6);   // one wave per (w,i) row
    int lane = threadIdx.x & 63;
    #pragma unroll
    for (int pass = 0; pass < 6; ++pass) {
        int j = pass * 64 + lane;
        int val = 0;
        if (j < L_)
            val = isU8 ? (int)m8[(size_t)row * L_ + j] : (int)m32[(size_t)row * L_ + j];
        u64 bits = __ballot(val != 0);
        if (lane == 0) pm[(size_t)row * 6 + pass] = bits;
    }
}

// ---------------- K4: QKV projection (fp32 in, fused bias+l2norm+scale, f16 out) ----------------
__global__ __launch_bounds__(256) void proj_kernel(
    const float* __restrict__ qx, const float* __restrict__ kx, const float* __restrict__ vx,
    const u16* __restrict__ wt, const float* __restrict__ bq, const float* __restrict__ bk,
    const float* __restrict__ scale,
    u16* __restrict__ pq, u16* __restrict__ pk, u16* __restrict__ pv)
{
    __shared__ u16 Al[64 * NKST];
    __shared__ u16 Bl[256 * NKST];
    const int mt = blockIdx.x, which = blockIdx.y, w = blockIdx.z;
    const float* X   = (which == 0) ? qx : ((which == 1) ? kx : vx);
    const u16* WT    = wt + which * 65536;
    const float* bias= (which == 0) ? bq : ((which == 1) ? bk : nullptr);
    u16* dst         = (which == 0) ? pq : ((which == 1) ? pk : pv);
    const int tid = threadIdx.x;
    const int wid = tid >> 6, lane = tid & 63, lr = lane & 15, lg = lane >> 4;
    const int r0 = tid >> 2, q4 = (tid & 3) * 8;
    const float* Xb = X + (size_t)w * L_ * 256;
    const f32x4 fz = {0.f, 0.f, 0.f, 0.f};
    f32x4 acc[4][4];
    #pragma unroll
    for (int i = 0; i < 4; ++i)
        #pragma unroll
        for (int j = 0; j < 4; ++j) acc[i][j] = fz;

    for (int kk = 0; kk < 8; ++kk) {
        __syncthreads();
        { // stage A (64 x 32 fp32 -> f16)
            int row = mt * 64 + r0;
            u16x8 u = {0,0,0,0,0,0,0,0};
            if (row < L_) {
                const float* s = Xb + row * 256 + kk * 32 + q4;
                f32x4 a = *(const f32x4*)s;
                f32x4 b = *(const f32x4*)(s + 4);
                #pragma unroll
                for (int j = 0; j < 4; ++j) { u[j] = f2h(a[j]); u[4+j] = f2h(b[j]); }
            }
            *(u16x8*)(&Al[r0 * NKST + q4]) = u;
        }
        { // stage B
            const u16* s = WT + tid * 256 + kk * 32;
            u16x8 b0 = *(const u16x8*)(s);
            u16x8 b1 = *(const u16x8*)(s + 8);
            u16x8 b2 = *(const u16x8*)(s + 16);
            u16x8 b3 = *(const u16x8*)(s + 24);
            u16* d = &Bl[tid * NKST];
            *(u16x8*)(d)      = b0;
            *(u16x8*)(d + 8)  = b1;
            *(u16x8*)(d + 16) = b2;
            *(u16x8*)(d + 24) = b3;
        }
        __syncthreads();
        h16x8 af[4];
        #pragma unroll
        for (int rf = 0; rf < 4; ++rf)
            af[rf] = *(const h16x8*)(&Al[(rf*16 + lr) * NKST + lg*8]);
        #pragma unroll
        for (int nf = 0; nf < 4; ++nf) {
            h16x8 b8 = *(const h16x8*)(&Bl[(wid*64 + nf*16 + lr) * NKST + lg*8]);
            #pragma unroll
            for (int rf = 0; rf < 4; ++rf)
                acc[rf][nf] = __builtin_amdgcn_mfma_f32_16x16x32_f16(af[rf], b8, acc[rf][nf], 0, 0, 0);
        }
    }
    // epilogue: +bias, l2norm (q/k), fold 1/max(scale,.01) into q, store f16
    const float sv = 1.0f / fmaxf(scale[0], 0.01f);
    #pragma unroll
    for (int hh = 0; hh < 2; ++hh) {
        const int h = 2 * wid + hh;
        float b0v = 0.f, b1v = 0.f;
        if (bias) { b0v = bias[h * 32 + lr]; b1v = bias[h * 32 + 16 + lr]; }
        #pragma unroll
        for (int rf = 0; rf < 4; ++rf) {
            #pragma unroll
            for (int reg = 0; reg < 4; ++reg) {
                float a0 = acc[rf][2*hh][reg] + b0v;
                float a1 = acc[rf][2*hh+1][reg] + b1v;
                float inv = 1.0f;
                if (which < 2) {
                    float ss = a0*a0 + a1*a1;
                    ss += __shfl_xor(ss, 1); ss += __shfl_xor(ss, 2);
                    ss += __shfl_xor(ss, 4); ss += __shfl_xor(ss, 8);
                    inv = 1.0f / fmaxf(sqrtf(ss), 1e-12f);
                    if (which == 0) inv *= sv;
                }
                int row = mt * 64 + rf * 16 + lg * 4 + reg;
                if (row < L_) {
                    u16* d = dst + (((size_t)w * H_ + h) * L_ + row) * HD_;
                    d[lr]      = f2h(a0 * inv);
                    d[16 + lr] = f2h(a1 * inv);
                }
            }
        }
    }
}

// ---------------- K5: attention per (w,h) ----------------
__global__ __launch_bounds__(256) void attn_kernel(
    const u16* __restrict__ pq, const u16* __restrict__ pk, const u16* __restrict__ pv,
    const float* __restrict__ table, const u16* __restrict__ e16,
    const u32* __restrict__ pm32, u16* __restrict__ ao)
{
    __shared__ u16 nk[LP_ * NKST];     // K, [key][hd]
    __shared__ u16 vT[HD_ * VTST];     // V transposed, [hd][key]
    __shared__ u16 nq[64 * NKST];      // Q tile
    __shared__ u16 Pw[4][16 * NKST];   // per-wave P chunk
    __shared__ float tableh[2197];

    const int h = blockIdx.x, w = blockIdx.y;
    const int tid = threadIdx.x;
    const int wid = tid >> 6, lane = tid & 63;
    const int lr = lane & 15, lg = lane >> 4;
    const u16* pkb = pk + ((size_t)(w * H_ + h)) * L_ * HD_;
    const u16* pvb = pv + ((size_t)(w * H_ + h)) * L_ * HD_;
    const u16* pqb = pq + ((size_t)(w * H_ + h)) * L_ * HD_;
    const int r0 = tid >> 2, q4 = (tid & 3) * 8;
    const f32x4 fz = {0.f, 0.f, 0.f, 0.f};

    for (int i = tid; i < 2197; i += 256) tableh[i] = table[i * 8 + h];

    // stage K
    #pragma unroll
    for (int pass = 0; pass < 6; ++pass) {
        int r = pass * 64 + r0;
        if (r < LP_) {
            u16x8 u = {0,0,0,0,0,0,0,0};
            if (r < L_) u = *(const u16x8*)(pkb + r * HD_ + q4);
            *(u16x8*)(&nk[r * NKST + q4]) = u;
        }
    }
    // stage V transposed
    #pragma unroll
    for (int pass = 0; pass < 6; ++pass) {
        int r = pass * 64 + r0;
        if (r < LP_) {
            u16x8 u = {0,0,0,0,0,0,0,0};
            if (r < L_) u = *(const u16x8*)(pvb + r * HD_ + q4);
            #pragma unroll
            for (int j = 0; j < 8; ++j) vT[(q4 + j) * VTST + r] = u[j];
        }
    }

    for (int qt = 0; qt < 6; ++qt) {
        const int qbase = qt * 64;
        __syncthreads();   // protect nq rewrite; first iter: nk/vT/tableh ready
        { // stage Q tile
            int r = qbase + r0;
            u16x8 u = {0,0,0,0,0,0,0,0};
            if (r < L_) u = *(const u16x8*)(pqb + r * HD_ + q4);
            *(u16x8*)(&nq[r0 * NKST + q4]) = u;
        }
        __syncthreads();

        // S = nq @ nk^T
        h16x8 aq = *(const h16x8*)(&nq[(wid * 16 + lr) * NKST + lg * 8]);
        f32x4 S[NF_];
        #pragma unroll
        for (int f = 0; f < NF_; ++f) {
            h16x8 b8 = *(const h16x8*)(&nk[(f * 16 + lr) * NKST + lg * 8]);
            S[f] = __builtin_amdgcn_mfma_f32_16x16x32_f16(aq, b8, fz, 0, 0, 0);
        }

        // logits: + bias LUT, mask bit, fp32 softmax
        const int rbase = qbase + wid * 16 + lg * 4;
        float mx[4] = {-1e30f, -1e30f, -1e30f, -1e30f};
        #pragma unroll
        for (int reg = 0; reg < 4; ++reg) {
            int row = rbase + reg;
            int br = (row < L_) ? row : (L_ - 1);
            const u16* er = e16 + (size_t)br * L_;
            const u32* pmrow = pm32 + ((size_t)w * L_ + br) * PMW;
            #pragma unroll
            for (int f = 0; f < NF_; ++f) {
                int col = f * 16 + lr;
                float lo;
                if (col < L_) {
                    lo = S[f][reg] + tableh[er[col]];
                    if ((pmrow[f >> 1] >> ((f & 1) * 16 + lr)) & 1) lo = -100000.0f;
                } else {
                    lo = -1e30f;
                }
                S[f][reg] = lo;
                mx[reg] = fmaxf(mx[reg], lo);
            }
        }
        #pragma unroll
        for (int reg = 0; reg < 4; ++reg)
            for (int d = 1; d < 16; d <<= 1)
                mx[reg] = fmaxf(mx[reg], __shfl_xor(mx[reg], d));
        float sm[4] = {0.f, 0.f, 0.f, 0.f};
        #pragma unroll
        for (int f = 0; f < NF_; ++f)
            #pragma unroll
            for (int reg = 0; reg < 4; ++reg) {
                float e = __expf(S[f][reg] - mx[reg]);
                S[f][reg] = e;
                sm[reg] += e;
            }
        #pragma unroll
        for (int reg = 0; reg < 4; ++reg)
            for (int d = 1; d < 16; d <<= 1)
                sm[reg] += __shfl_xor(sm[reg], d);
        float rv[4];
        #pragma unroll
        for (int reg = 0; reg < 4; ++reg) rv[reg] = 1.0f / sm[reg];

        // PV
        f32x4 O0 = fz, O1 = fz;
        u16* Pm = &Pw[wid][0];
        #pragma unroll
        for (int cc = 0; cc < 11; ++cc) {
            #pragma unroll
            for (int half = 0; half < 2; ++half) {
                int f = cc * 2 + half;
                #pragma unroll
                for (int reg = 0; reg < 4; ++reg)
                    Pm[(lg * 4 + reg) * NKST + half * 16 + lr] = f2h(S[f][reg] * rv[reg]);
            }
            h16x8 pa = *(const h16x8*)(&Pm[lr * NKST + lg * 8]);
            h16x8 v0 = *(const h16x8*)(&vT[lr * VTST + cc * 32 + lg * 8]);
            h16x8 v1 = *(const h16x8*)(&vT[(16 + lr) * VTST + cc * 32 + lg * 8]);
            O0 = __builtin_amdgcn_mfma_f32_16x16x32_f16(pa, v0, O0, 0, 0, 0);
            O1 = __builtin_amdgcn_mfma_f32_16x16x32_f16(pa, v1, O1, 0, 0, 0);
        }
        #pragma unroll
        for (int reg = 0; reg < 4; ++reg) {
            int row = rbase + reg;
            if (row < L_) {
                size_t o = ((size_t)w * L_ + row) * 256 + h * HD_;
                ao[o + lr]      = f2h(O0[reg]);
                ao[o + 16 + lr] = f2h(O1[reg]);
            }
        }
    }
}

// ---------------- K6: output projection (f16 in -> fp32 out) ----------------
__global__ __launch_bounds__(256) void outproj_kernel(
    const u16* __restrict__ ao, const u16* __restrict__ WT,
    const float* __restrict__ bw, float* __restrict__ out)
{
    __shared__ u16 Al[64 * NKST];
    __shared__ u16 Bl[256 * NKST];
    const int mt = blockIdx.x;
    const int tid = threadIdx.x;
    const int wid = tid >> 6, lane = tid & 63, lr = lane & 15, lg = lane >> 4;
    const int r0 = tid >> 2, q4 = (tid & 3) * 8;
    const f32x4 fz = {0.f, 0.f, 0.f, 0.f};
    f32x4 acc[4][4];
    #pragma unroll
    for (int i = 0; i < 4; ++i)
        #pragma unroll
        for (int j = 0; j < 4; ++j) acc[i][j] = fz;

    for (int kk = 0; kk < 8; ++kk) {
        __syncthreads();
        {
            int row = mt * 64 + r0;
            u16x8 u = *(const u16x8*)(ao + (size_t)row * 256 + kk * 32 + q4);
            *(u16x8*)(&Al[r0 * NKST + q4]) = u;
        }
        {
            const u16* s = WT + tid * 256 + kk * 32;
            u16x8 b0 = *(const u16x8*)(s);
            u16x8 b1 = *(const u16x8*)(s + 8);
            u16x8 b2 = *(const u16x8*)(s + 16);
            u16x8 b3 = *(const u16x8*)(s + 24);
            u16* d = &Bl[tid * NKST];
            *(u16x8*)(d)      = b0;
            *(u16x8*)(d + 8)  = b1;
            *(u16x8*)(d + 16) = b2;
            *(u16x8*)(d + 24) = b3;
        }
        __syncthreads();
        h16x8 af[4];
        #pragma unroll
        for (int rf = 0; rf < 4; ++rf)
            af[rf] = *(const h16x8*)(&Al[(rf*16 + lr) * NKST + lg*8]);
        #pragma unroll
        for (int nf = 0; nf < 4; ++nf) {
            h16x8 b8 = *(const h16x8*)(&Bl[(wid*64 + nf*16 + lr) * NKST + lg*8]);
            #pragma unroll
            for (int rf = 0; rf < 4; ++rf)
                acc[rf][nf] = __builtin_amdgcn_mfma_f32_16x16x32_f16(af[rf], b8, acc[rf][nf], 0, 0, 0);
        }
    }
    #pragma unroll
    for (int nf = 0; nf < 4; ++nf) {
        int col = wid * 64 + nf * 16 + lr;
        float bv = bw[col];
        #pragma unroll
        for (int rf = 0; rf < 4; ++rf) {
            #pragma unroll
            for (int reg = 0; reg < 4; ++reg) {
                int row = mt * 64 + rf * 16 + lg * 4 + reg;
                out[(size_t)row * 256 + col] = acc[rf][nf][reg] + bv;
            }
        }
    }
}

extern "C" void kernel_launch(void* const* d_in, const int* in_sizes, int n_in,
                              void* d_out, int out_size, void* d_ws, size_t ws_size,
                              hipStream_t stream) {
    const float* q    = (const float*)d_in[0];
    const float* k    = (const float*)d_in[1];
    const float* v    = (const float*)d_in[2];
    const float* idxf = (const float*)d_in[3];
    const u32*   mask = (const u32*)d_in[4];
    const float* Wq   = (const float*)d_in[5];
    const float* bq   = (const float*)d_in[6];
    const float* Wk   = (const float*)d_in[7];
    const float* bk   = (const float*)d_in[8];
    const float* Wv   = (const float*)d_in[9];
    const float* Ww   = (const float*)d_in[10];
    const float* bw   = (const float*)d_in[11];
    const float* scale= (const float*)d_in[12];
    const float* W1   = (const float*)d_in[13];
    const float* b1   = (const float*)d_in[14];
    const float* W2   = (const float*)d_in[15];
    const float* b2   = (const float*)d_in[16];
    float* out = (float*)d_out;

    char* ws = (char*)d_ws;
    size_t off = 0;
    auto take = [&](size_t nbytes) -> void* {
        void* p = (void*)(ws + off);
        off += (nbytes + 255) & ~(size_t)255;
        return p;
    };
    u16*   wt    = (u16*)  take((size_t)4 * 65536 * 2);
    float* table = (float*)take((size_t)2197 * 8 * 4);
    u16*   e16   = (u16*)  take((size_t)LL_ * 2);
    u64*   pm    = (u64*)  take((size_t)NW_ * L_ * 6 * 8);
    const size_t PN = (size_t)NW_ * H_ * L_ * HD_;      // 11,239,424
    u16* pq = (u16*)take(PN * 2);
    u16* pk = (u16*)take(PN * 2);
    u16* pv = (u16*)take(PN * 2);
    u16* ao = (u16*)take(PN * 2);
    if (off > ws_size) return;   // workspace too small: output stays zero -> flags clearly

    hipLaunchKernelGGL(cvtw_kernel, dim3(64, 4), dim3(256), 0, stream, Wq, Wk, Wv, Ww, wt);
    hipLaunchKernelGGL(cpb_table_kernel, dim3(2197), dim3(256), 0, stream, W1, b1, W2, b2, table);
    hipLaunchKernelGGL(e16_kernel, dim3((LL_ + 255) / 256), dim3(256), 0, stream, idxf, e16);
    hipLaunchKernelGGL(pack_mask_kernel, dim3(NW_ * L_ / 4), dim3(256), 0, stream, mask, pm);
    hipLaunchKernelGGL(proj_kernel, dim3(6, 3, NW_), dim3(256), 0, stream,
                       q, k, v, wt, bq, bk, scale, pq, pk, pv);
    hipLaunchKernelGGL(attn_kernel, dim3(H_, NW_), dim3(256), 0, stream,
                       pq, pk, pv, table, e16, (const u32*)pm, ao);
    hipLaunchKernelGGL(outproj_kernel, dim3(686), dim3(256), 0, stream,
                       ao, wt + 3 * 65536, bw, out);
}